// Round 1
// baseline (198.180 us; speedup 1.0000x reference)
//
#include <hip/hip_runtime.h>
#include <math.h>

#define DD 192
#define HH 192
#define WW 192
#define NVOX (DD*HH*WW)        // 7077888
#define NV4  (NVOX/4)          // 1769472
#define RB   1024              // reduction blocks
#define RT   256               // reduction threads per block

__device__ __forceinline__ float gcoord(int i, int n) {
    return -1.0f + (float)i * (2.0f / (float)(n - 1));
}

// quantities: 0:sum_x 1:sum x*gx 2:sum x*gy 3:sum x*gz  4..7: same for y
__global__ void reduce_kernel(const float* __restrict__ x,
                              const float* __restrict__ y,
                              double* __restrict__ partials) {
    double acc[8] = {0,0,0,0,0,0,0,0};
    int tid = blockIdx.x * blockDim.x + threadIdx.x;
    const float4* x4 = (const float4*)x;
    const float4* y4 = (const float4*)y;
    for (int i = tid; i < NV4; i += RB * RT) {
        float4 xv = x4[i];
        float4 yv = y4[i];
        int base = i * 4;
        int w = base % WW;          // multiple of 4
        int rem = base / WW;
        int h = rem % HH;
        int d = rem / HH;
        float gy = gcoord(h, HH);
        float gz = gcoord(d, DD);
        float xs[4] = {xv.x, xv.y, xv.z, xv.w};
        float ys[4] = {yv.x, yv.y, yv.z, yv.w};
        #pragma unroll
        for (int k = 0; k < 4; ++k) {
            float gx = gcoord(w + k, WW);
            acc[0] += (double)xs[k];
            acc[1] += (double)(xs[k] * gx);
            acc[2] += (double)(xs[k] * gy);
            acc[3] += (double)(xs[k] * gz);
            acc[4] += (double)ys[k];
            acc[5] += (double)(ys[k] * gx);
            acc[6] += (double)(ys[k] * gy);
            acc[7] += (double)(ys[k] * gz);
        }
    }
    // wave (64-lane) butterfly reduce each quantity
    #pragma unroll
    for (int q = 0; q < 8; ++q) {
        double v = acc[q];
        #pragma unroll
        for (int off = 32; off > 0; off >>= 1)
            v += __shfl_down(v, off, 64);
        acc[q] = v;
    }
    __shared__ double lds[4][8];
    int lane = threadIdx.x & 63;
    int wave = threadIdx.x >> 6;
    if (lane == 0) {
        #pragma unroll
        for (int q = 0; q < 8; ++q) lds[wave][q] = acc[q];
    }
    __syncthreads();
    if (threadIdx.x < 8) {
        int q = threadIdx.x;
        double s = lds[0][q] + lds[1][q] + lds[2][q] + lds[3][q];
        partials[q * RB + blockIdx.x] = s;   // deterministic, no atomics
    }
}

__global__ void finalize_kernel(const double* __restrict__ partials,
                                float* __restrict__ tvec) {
    __shared__ double red[256];
    double sums[8];
    for (int q = 0; q < 8; ++q) {
        double s = 0.0;
        for (int i = threadIdx.x; i < RB; i += 256) s += partials[q * RB + i];
        red[threadIdx.x] = s;
        __syncthreads();
        for (int stride = 128; stride > 0; stride >>= 1) {
            if (threadIdx.x < stride) red[threadIdx.x] += red[threadIdx.x + stride];
            __syncthreads();
        }
        if (threadIdx.x == 0) sums[q] = red[0];
        __syncthreads();
    }
    if (threadIdx.x == 0) {
        double tx = sums[1] / sums[0] - sums[5] / sums[4];
        double ty = sums[2] / sums[0] - sums[6] / sums[4];
        double tz = sums[3] / sums[0] - sums[7] / sums[4];
        tvec[0] = (float)tx;
        tvec[1] = (float)ty;
        tvec[2] = (float)tz;
    }
}

__global__ void main_kernel(const float* __restrict__ x,
                            const float* __restrict__ tvec,
                            float* __restrict__ out_t,
                            float* __restrict__ out_g) {
    int idx = blockIdx.x * blockDim.x + threadIdx.x;
    if (idx >= NVOX) return;
    float tx = tvec[0], ty = tvec[1], tz = tvec[2];
    int w = idx % WW;
    int rem = idx / WW;
    int h = rem % HH;
    int d = rem / HH;
    float gx = gcoord(w, WW) + tx;
    float gy = gcoord(h, HH) + ty;
    float gz = gcoord(d, DD) + tz;
    // grid output, layout (d,h,w,3) — adjacent scalar stores merge to dwordx3
    out_g[3 * idx + 0] = gx;
    out_g[3 * idx + 1] = gy;
    out_g[3 * idx + 2] = gz;
    // trilinear sample of x at (gx,gy,gz)
    float ix = (gx + 1.0f) * 0.5f * (float)(WW - 1);
    float iy = (gy + 1.0f) * 0.5f * (float)(HH - 1);
    float iz = (gz + 1.0f) * 0.5f * (float)(DD - 1);
    float fx = floorf(ix), fy = floorf(iy), fz = floorf(iz);
    float wx = ix - fx, wy = iy - fy, wz = iz - fz;
    int ix0 = (int)fx, iy0 = (int)fy, iz0 = (int)fz;
    float acc = 0.0f;
    #pragma unroll
    for (int dz = 0; dz < 2; ++dz) {
        int zi = iz0 + dz;
        if ((unsigned)zi >= (unsigned)DD) continue;   // zero-weight (valid mask)
        float wzz = dz ? wz : 1.0f - wz;
        #pragma unroll
        for (int dy = 0; dy < 2; ++dy) {
            int yi = iy0 + dy;
            if ((unsigned)yi >= (unsigned)HH) continue;
            float wyy = dy ? wy : 1.0f - wy;
            #pragma unroll
            for (int dx = 0; dx < 2; ++dx) {
                int xi = ix0 + dx;
                if ((unsigned)xi >= (unsigned)WW) continue;
                float wxx = dx ? wx : 1.0f - wx;
                acc += x[(zi * HH + yi) * WW + xi] * (wzz * wyy * wxx);
            }
        }
    }
    out_t[idx] = acc;
}

extern "C" void kernel_launch(void* const* d_in, const int* in_sizes, int n_in,
                              void* d_out, int out_size, void* d_ws, size_t ws_size,
                              hipStream_t stream) {
    const float* x = (const float*)d_in[0];
    const float* y = (const float*)d_in[1];
    float* out = (float*)d_out;
    float* out_t = out;            // transformed: NVOX floats
    float* out_g = out + NVOX;     // grid_b: NVOX*3 floats
    double* partials = (double*)d_ws;                       // 8*RB doubles = 64 KiB
    float* tvec = (float*)((char*)d_ws + 8 * RB * sizeof(double));
    reduce_kernel<<<RB, RT, 0, stream>>>(x, y, partials);
    finalize_kernel<<<1, 256, 0, stream>>>(partials, tvec);
    main_kernel<<<(NVOX + 255) / 256, 256, 0, stream>>>(x, tvec, out_t, out_g);
}

// Round 2
// 174.736 us; speedup vs baseline: 1.1342x; 1.1342x over previous
//
#include <hip/hip_runtime.h>
#include <math.h>

#define DD 192
#define HH 192
#define WW 192
#define NVOX (DD*HH*WW)        // 7077888
#define NV4  (NVOX/4)          // 1769472
#define RB   1024              // reduction blocks
#define RT   256               // reduction threads per block

struct Consts {
    float tx, ty, tz;          // grid translation
    float wgt[8];              // corner weights, index = dz*4+dy*2+dx
    int   dx0, dy0, dz0;       // integer corner offsets (floor of shift)
};

__device__ __forceinline__ float gcoord(int i, int n) {
    return -1.0f + (float)i * (2.0f / (float)(n - 1));
}

// quantities: 0:sum_x 1:sum x*gx 2:sum x*gy 3:sum x*gz  4..7: same for y
__global__ void reduce_kernel(const float* __restrict__ x,
                              const float* __restrict__ y,
                              double* __restrict__ partials) {
    double acc[8] = {0,0,0,0,0,0,0,0};
    int tid = blockIdx.x * blockDim.x + threadIdx.x;
    const float4* x4 = (const float4*)x;
    const float4* y4 = (const float4*)y;
    for (int i = tid; i < NV4; i += RB * RT) {
        float4 xv = x4[i];
        float4 yv = y4[i];
        int base = i * 4;
        int w = base % WW;          // multiple of 4
        int rem = base / WW;
        int h = rem % HH;
        int d = rem / HH;
        float gy = gcoord(h, HH);
        float gz = gcoord(d, DD);
        float xs[4] = {xv.x, xv.y, xv.z, xv.w};
        float ys[4] = {yv.x, yv.y, yv.z, yv.w};
        #pragma unroll
        for (int k = 0; k < 4; ++k) {
            float gx = gcoord(w + k, WW);
            acc[0] += (double)xs[k];
            acc[1] += (double)(xs[k] * gx);
            acc[2] += (double)(xs[k] * gy);
            acc[3] += (double)(xs[k] * gz);
            acc[4] += (double)ys[k];
            acc[5] += (double)(ys[k] * gx);
            acc[6] += (double)(ys[k] * gy);
            acc[7] += (double)(ys[k] * gz);
        }
    }
    #pragma unroll
    for (int q = 0; q < 8; ++q) {
        double v = acc[q];
        #pragma unroll
        for (int off = 32; off > 0; off >>= 1)
            v += __shfl_down(v, off, 64);
        acc[q] = v;
    }
    __shared__ double lds[4][8];
    int lane = threadIdx.x & 63;
    int wave = threadIdx.x >> 6;
    if (lane == 0) {
        #pragma unroll
        for (int q = 0; q < 8; ++q) lds[wave][q] = acc[q];
    }
    __syncthreads();
    if (threadIdx.x < 8) {
        int q = threadIdx.x;
        partials[q * RB + blockIdx.x] = lds[0][q] + lds[1][q] + lds[2][q] + lds[3][q];
    }
}

__global__ void finalize_kernel(const double* __restrict__ partials,
                                Consts* __restrict__ cs) {
    // per-thread strided partial sums for all 8 quantities, then wave reduce
    double s[8];
    #pragma unroll
    for (int q = 0; q < 8; ++q) {
        double v = 0.0;
        for (int i = threadIdx.x; i < RB; i += 256) v += partials[q * RB + i];
        #pragma unroll
        for (int off = 32; off > 0; off >>= 1)
            v += __shfl_down(v, off, 64);
        s[q] = v;
    }
    __shared__ double lds[4][8];
    int lane = threadIdx.x & 63;
    int wave = threadIdx.x >> 6;
    if (lane == 0) {
        #pragma unroll
        for (int q = 0; q < 8; ++q) lds[wave][q] = s[q];
    }
    __syncthreads();
    if (threadIdx.x == 0) {
        double sums[8];
        #pragma unroll
        for (int q = 0; q < 8; ++q)
            sums[q] = lds[0][q] + lds[1][q] + lds[2][q] + lds[3][q];
        double tx = sums[1] / sums[0] - sums[5] / sums[4];
        double ty = sums[2] / sums[0] - sums[6] / sums[4];
        double tz = sums[3] / sums[0] - sums[7] / sums[4];
        cs->tx = (float)tx; cs->ty = (float)ty; cs->tz = (float)tz;
        // sample position: ix = w + cx, cx = tx*(W-1)/2 — constant shift
        double cx = tx * (double)(WW - 1) * 0.5;
        double cy = ty * (double)(HH - 1) * 0.5;
        double cz = tz * (double)(DD - 1) * 0.5;
        double fx = floor(cx), fy = floor(cy), fz = floor(cz);
        float wx = (float)(cx - fx), wy = (float)(cy - fy), wz = (float)(cz - fz);
        cs->dx0 = (int)fx; cs->dy0 = (int)fy; cs->dz0 = (int)fz;
        #pragma unroll
        for (int k = 0; k < 8; ++k) {
            float wzz = (k & 4) ? wz : 1.0f - wz;
            float wyy = (k & 2) ? wy : 1.0f - wy;
            float wxx = (k & 1) ? wx : 1.0f - wx;
            cs->wgt[k] = wzz * wyy * wxx;
        }
    }
}

// Fused: grid write (LDS-staged, coalesced float4) + constant-shift trilinear stencil
__global__ void __launch_bounds__(256) main_kernel(const float* __restrict__ x,
                                                   const Consts* __restrict__ csp,
                                                   float* __restrict__ out_t,
                                                   float4* __restrict__ out_g4) {
    __shared__ float gbuf[768];         // 256 voxels * 3 comps
    const Consts c = *csp;              // uniform address -> scalar loads
    int idx = blockIdx.x * 256 + threadIdx.x;
    int w = idx % WW;
    int rem = idx / WW;
    int h = rem % HH;
    int d = rem / HH;
    float gx = gcoord(w, WW) + c.tx;
    float gy = gcoord(h, HH) + c.ty;
    float gz = gcoord(d, DD) + c.tz;
    gbuf[3 * threadIdx.x + 0] = gx;
    gbuf[3 * threadIdx.x + 1] = gy;
    gbuf[3 * threadIdx.x + 2] = gz;
    __syncthreads();
    if (threadIdx.x < 192) {
        const float4* src = (const float4*)gbuf;
        out_g4[blockIdx.x * 192 + threadIdx.x] = src[threadIdx.x];
    }
    // trilinear: constant integer shift + constant weights, branchless validity
    int xi0 = w + c.dx0, yi0 = h + c.dy0, zi0 = d + c.dz0;
    int xi1 = xi0 + 1,  yi1 = yi0 + 1,  zi1 = zi0 + 1;
    int xs0 = min(max(xi0, 0), WW - 1), xs1 = min(max(xi1, 0), WW - 1);
    int ys0 = min(max(yi0, 0), HH - 1), ys1 = min(max(yi1, 0), HH - 1);
    int zs0 = min(max(zi0, 0), DD - 1), zs1 = min(max(zi1, 0), DD - 1);
    float vx0 = ((unsigned)xi0 < (unsigned)WW) ? 1.0f : 0.0f;
    float vx1 = ((unsigned)xi1 < (unsigned)WW) ? 1.0f : 0.0f;
    float vy0 = ((unsigned)yi0 < (unsigned)HH) ? 1.0f : 0.0f;
    float vy1 = ((unsigned)yi1 < (unsigned)HH) ? 1.0f : 0.0f;
    float vz0 = ((unsigned)zi0 < (unsigned)DD) ? 1.0f : 0.0f;
    float vz1 = ((unsigned)zi1 < (unsigned)DD) ? 1.0f : 0.0f;
    int rb00 = (zs0 * HH + ys0) * WW;
    int rb01 = (zs0 * HH + ys1) * WW;
    int rb10 = (zs1 * HH + ys0) * WW;
    int rb11 = (zs1 * HH + ys1) * WW;
    float acc =
        x[rb00 + xs0] * (c.wgt[0] * (vz0 * vy0 * vx0)) +
        x[rb00 + xs1] * (c.wgt[1] * (vz0 * vy0 * vx1)) +
        x[rb01 + xs0] * (c.wgt[2] * (vz0 * vy1 * vx0)) +
        x[rb01 + xs1] * (c.wgt[3] * (vz0 * vy1 * vx1)) +
        x[rb10 + xs0] * (c.wgt[4] * (vz1 * vy0 * vx0)) +
        x[rb10 + xs1] * (c.wgt[5] * (vz1 * vy0 * vx1)) +
        x[rb11 + xs0] * (c.wgt[6] * (vz1 * vy1 * vx0)) +
        x[rb11 + xs1] * (c.wgt[7] * (vz1 * vy1 * vx1));
    out_t[idx] = acc;
}

extern "C" void kernel_launch(void* const* d_in, const int* in_sizes, int n_in,
                              void* d_out, int out_size, void* d_ws, size_t ws_size,
                              hipStream_t stream) {
    const float* x = (const float*)d_in[0];
    const float* y = (const float*)d_in[1];
    float* out = (float*)d_out;
    float* out_t = out;                   // transformed: NVOX floats
    float4* out_g4 = (float4*)(out + NVOX); // grid: NVOX*3 floats, 16B-aligned
    double* partials = (double*)d_ws;     // 8*RB doubles = 64 KiB
    Consts* cs = (Consts*)((char*)d_ws + 8 * RB * sizeof(double));
    reduce_kernel<<<RB, RT, 0, stream>>>(x, y, partials);
    finalize_kernel<<<1, 256, 0, stream>>>(partials, cs);
    main_kernel<<<NVOX / 256, 256, 0, stream>>>(x, cs, out_t, out_g4);
}